// Round 8
// baseline (279.670 us; speedup 1.0000x reference)
//
#include <hip/hip_runtime.h>

typedef unsigned short u16;
typedef unsigned int u32;
typedef unsigned long long u64;

#define NB 4
#define NTOK 12544
#define NBHD 48
#define DIM 256
#define OUTD 512
#define KEEPN 3136
#define SAMPLEN 2352
#define RESN 784
#define GW 112
#define POSN (NB * KEEPN * 2)   // 25088 floats
#define QTR (NTOK / 4)          // 3136
#define NBKT 16384

// fallback in-place GEMM tiling
#define BLKM 128
#define BLKN 256
#define BROW 40

// ws fast-path layout (bytes)
#define XWS_BYTES   (25690112ull)                 // 12544*1024*2 (bf16 X, in-place LN)
#define WTAB_BYTES  (9633792ull)                  // 12544*48*16 (f32x4 edge weights)
#define LINT_BYTES  (1048576ull)                  // 512*1024*2
#define SLOTS_BYTES (401408ull)                   // 4*12544*8
#define PART_BYTES  (786432ull)                   // hist+base+cursor
#define XWS_OFF   0ull
#define WTAB_OFF  (XWS_OFF + XWS_BYTES)
#define LINT_OFF  (WTAB_OFF + WTAB_BYTES)
#define SLOTS_OFF (LINT_OFF + LINT_BYTES)
#define HIST_OFF  (SLOTS_OFF + SLOTS_BYTES)
#define WS_NEED   (HIST_OFF + PART_BYTES)

__device__ __forceinline__ float bf2f(u16 u) {
    union { u32 i; float f; } v; v.i = ((u32)u) << 16; return v.f;
}
__device__ __forceinline__ u16 f2bf(float f) {
    union { u32 i; float f; } v; v.f = f;
    return (u16)((v.i + 0x7FFFu + ((v.i >> 16) & 1u)) >> 16);
}

typedef __bf16 bf16x8 __attribute__((ext_vector_type(8)));
typedef float floatx4 __attribute__((ext_vector_type(4)));

// final_prob, bit-exact vs reference f32 arithmetic
__device__ __forceinline__ float make_f(float lp, int n) {
    int i = n / GW, j = n % GW;
    float f = lp * 4.0f;
    if (((i | j) & 1) == 0) f = 1.0f + f;        // grid_prob (stride 2)
    if (((i | j) & 3) == 0) f = f + (-100.0f);   // reserve penalty (stride 4)
    return f;
}
// key: descending order == top_k order; ties -> lower n first
__device__ __forceinline__ u64 f_to_key(float f, int n) {
    union { float f; u32 u; } v; v.f = f;
    u32 m = (v.u & 0x80000000u) ? ~v.u : (v.u | 0x80000000u);
    return (((u64)m) << 32) | (u64)(0xFFFFFFFFu - (u32)n);
}
__device__ __forceinline__ int f_to_bucket(float f) {
    int b = (int)floorf(f * 3276.8f);            // monotone: [0,5) -> [0,16384)
    return b < 0 ? 0 : (b > NBKT - 1 ? NBKT - 1 : b);
}

// ---- convert+transpose lin_w -> linT (512x1024 bf16); also zero hist ------
__global__ __launch_bounds__(256) void linT_cvt_kernel(
    const float* __restrict__ lin_w, u16* __restrict__ linT,
    u32* __restrict__ hist) {
    __shared__ u16 T[64 * 65];
    int k0 = blockIdx.x * 64, n0 = blockIdx.y * 64;
    int t = threadIdx.x;
    int bid = blockIdx.y * 16 + blockIdx.x;      // 128 blocks x 512 = 65536
    hist[bid * 512 + t] = 0;
    hist[bid * 512 + 256 + t] = 0;
    int r = t >> 2, c4 = (t & 3) * 16;
#pragma unroll
    for (int i = 0; i < 4; ++i) {
        float4 v = *(const float4*)&lin_w[(size_t)(k0 + r) * OUTD + n0 + c4 + i * 4];
        T[(c4 + i * 4 + 0) * 65 + r] = f2bf(v.x);
        T[(c4 + i * 4 + 1) * 65 + r] = f2bf(v.y);
        T[(c4 + i * 4 + 2) * 65 + r] = f2bf(v.z);
        T[(c4 + i * 4 + 3) * 65 + r] = f2bf(v.w);
    }
    __syncthreads();
    int nl = t >> 2, kc = (t & 3) * 16;
    union { uint4 v[2]; u16 h[16]; } u;
#pragma unroll
    for (int i = 0; i < 16; ++i) u.h[i] = T[nl * 65 + kc + i];
    u16* dst = &linT[(size_t)(n0 + nl) * 1024 + k0 + kc];
    *(uint4*)(dst + 0) = u.v[0];
    *(uint4*)(dst + 8) = u.v[1];
}

// ================= selection: exact counting-sort top-k =====================
__global__ __launch_bounds__(256) void hist_kernel(
    const float* __restrict__ lprob, u32* __restrict__ hist) {
    int g = blockIdx.x * 256 + threadIdx.x;
    int b = g / NTOK, n = g % NTOK;
    int bkt = f_to_bucket(make_f(lprob[g], n));
    atomicAdd(&hist[b * NBKT + bkt], 1u);
}

__global__ __launch_bounds__(1024) void prefix_kernel(
    const u32* __restrict__ hist, u32* __restrict__ base, u32* __restrict__ cursor) {
    int b = blockIdx.x, t = threadIdx.x;
    const u32* h = hist + b * NBKT;
    u32 loc[16], own = 0;
#pragma unroll
    for (int i = 0; i < 16; ++i) { loc[i] = h[t * 16 + i]; own += loc[i]; }
    __shared__ u32 buf[2][1024];
    buf[0][t] = own;
    __syncthreads();
    int src = 0;
    for (int off = 1; off < 1024; off <<= 1) {
        u32 v = buf[src][t] + ((t + off < 1024) ? buf[src][t + off] : 0u);
        buf[src ^ 1][t] = v;
        src ^= 1;
        __syncthreads();
    }
    u32 above = buf[src][t] - own;
    u32 suf = 0, bout[16];
    for (int i = 15; i >= 0; --i) { bout[i] = above + suf; suf += loc[i]; }
    u32* bb = base + b * NBKT;
    u32* cc = cursor + b * NBKT;
#pragma unroll
    for (int i = 0; i < 16; ++i) { bb[t * 16 + i] = bout[i]; cc[t * 16 + i] = bout[i]; }
}

__global__ __launch_bounds__(256) void scatter_kernel(
    const float* __restrict__ lprob, u32* __restrict__ cursor,
    u64* __restrict__ slots) {
    int g = blockIdx.x * 256 + threadIdx.x;
    int b = g / NTOK, n = g % NTOK;
    float f = make_f(lprob[g], n);
    int bkt = f_to_bucket(f);
    u32 s = atomicAdd(&cursor[b * NBKT + bkt], 1u);
    slots[b * NTOK + s] = f_to_key(f, n);
}

__global__ __launch_bounds__(256) void rank_finalize_kernel(
    const float* __restrict__ lprob, const u32* __restrict__ hist,
    const u32* __restrict__ base, const u64* __restrict__ slots,
    float* __restrict__ pos_out) {
    int g = blockIdx.x * 256 + threadIdx.x;
    int b = g / NTOK, n = g % NTOK;
    int i = n / GW, j = n % GW;
    if (((i | j) & 3) == 0) {
        int r = (i >> 2) * 28 + (j >> 2);
        int slot = b * KEEPN + SAMPLEN + r;
        pos_out[slot * 2 + 0] = (float)i;
        pos_out[slot * 2 + 1] = (float)j;
        return;
    }
    float f = make_f(lprob[g], n);
    int bkt = f_to_bucket(f);
    u32 r0 = base[b * NBKT + bkt];
    if (r0 >= SAMPLEN) return;
    u64 my = f_to_key(f, n);
    u32 cnt = hist[b * NBKT + bkt];
    const u64* sl = slots + b * NTOK + r0;
    u32 rank = r0;
    for (u32 s = 0; s < cnt; ++s) rank += (sl[s] > my) ? 1u : 0u;
    if (rank < SAMPLEN) {
        int slot = b * KEEPN + (int)rank;
        pos_out[slot * 2 + 0] = (float)i;
        pos_out[slot * 2 + 1] = (float)j;
    }
}

// ---- wtab: per-edge weight-net -> wtab[t][48] (float4) --------------------
__global__ __launch_bounds__(256) void wtab_kernel(
    const float* __restrict__ pos_in, const int* __restrict__ member_idx,
    const int* __restrict__ pe_idx, const float* __restrict__ cmask,
    const float* __restrict__ lprob, const float* __restrict__ pre_table,
    const float* __restrict__ w1, const float* __restrict__ b1,
    const float* __restrict__ g1, const float* __restrict__ bb1,
    float4* __restrict__ wtab) {
    int g = blockIdx.x * 256 + threadIdx.x;      // 2352 blocks -> 602112 edges
    int t = g / NBHD, k = g - t * NBHD;
    int b = t / KEEPN;
    int n_src = (int)pos_in[t * 2 + 0] * GW + (int)pos_in[t * 2 + 1];
    int e = (b * NTOK + n_src) * NBHD + k;
    int mem = member_idx[e];
    int pe = pe_idx[e];
    float cm = cmask[e];
    float lpe = lprob[b * NTOK + mem];
    float z[4];
#pragma unroll
    for (int m = 0; m < 4; ++m) {
        float acc = b1[m];
#pragma unroll
        for (int d = 0; d < 5; ++d) acc += pre_table[pe * 5 + d] * w1[d * 4 + m];
        z[m] = acc;
    }
    float mean = (z[0] + z[1] + z[2] + z[3]) * 0.25f;
    float var = 0.0f;
#pragma unroll
    for (int m = 0; m < 4; ++m) { float d = z[m] - mean; var += d * d; }
    float rstd = rsqrtf(var * 0.25f + 1e-5f);
    float sc = lpe * cm;
    float wv[4];
#pragma unroll
    for (int m = 0; m < 4; ++m) {
        float y = (z[m] - mean) * rstd * g1[m] + bb1[m];
        wv[m] = 0.5f * y * (1.0f + erff(y * 0.70710678118654752f)) * sc;
    }
    wtab[g] = make_float4(wv[0], wv[1], wv[2], wv[3]);
}

// ---- token v4: channel-tiled gather; writes pre-LN bf16 X -----------------
// grid (784, 8): y = 32-channel tile (slow dim -> L2-resident 1.6MB slab/XCD),
// x swizzled for batch->XCD affinity. Block = 16 tokens, 4 waves x 4 tokens.
__global__ __launch_bounds__(256) void token_v4_kernel(
    const float* __restrict__ pos_in, const float4* __restrict__ wtab,
    const int* __restrict__ member_idx, const float* __restrict__ feat,
    u16* __restrict__ xws) {
    __shared__ int nsrc_s[16];
    __shared__ int mem_s[16][NBHD];
    __shared__ __align__(16) float4 w_s[16][NBHD];

    int x = blockIdx.x;
    int xcd = x & 7, j = x >> 3;                 // j in [0,98)
    int b = xcd >> 1;
    int t0 = b * KEEPN + ((xcd & 1) * 98 + j) * 16;
    int tile = blockIdx.y;
    int ch0 = tile * 32;
    int tid = threadIdx.x;
    int wave = tid >> 6, lane = tid & 63;
    int r4 = lane >> 4, cp = lane & 15;

    if (tid < 16)
        nsrc_s[tid] = (int)pos_in[(t0 + tid) * 2 + 0] * GW +
                      (int)pos_in[(t0 + tid) * 2 + 1];
    __syncthreads();
#pragma unroll
    for (int e = tid; e < 16 * NBHD; e += 256) {
        int tok = e / NBHD, k = e - tok * NBHD;
        mem_s[tok][k] = member_idx[(b * NTOK + nsrc_s[tok]) * NBHD + k];
        ((float4*)w_s)[e] = wtab[(t0 + tok) * NBHD + k];
    }
    __syncthreads();

    const float* fb = feat + (size_t)b * NTOK * DIM + ch0 + cp * 2;
#pragma unroll
    for (int tt = 0; tt < 4; ++tt) {
        int tok = wave * 4 + tt;
        float a[8] = {0.f, 0.f, 0.f, 0.f, 0.f, 0.f, 0.f, 0.f};
#pragma unroll
        for (int i = 0; i < 12; ++i) {
            int row = i * 4 + r4;
            int mem = mem_s[tok][row];           // broadcast (same addr/16 lanes)
            float4 w = w_s[tok][row];            // broadcast
            float2 g = *(const float2*)(fb + (size_t)mem * DIM);
            a[0] += w.x * g.x; a[1] += w.y * g.x; a[2] += w.z * g.x; a[3] += w.w * g.x;
            a[4] += w.x * g.y; a[5] += w.y * g.y; a[6] += w.z * g.y; a[7] += w.w * g.y;
        }
#pragma unroll
        for (int i = 0; i < 8; ++i) {
            a[i] += __shfl_xor(a[i], 16, 64);
            a[i] += __shfl_xor(a[i], 32, 64);
        }
        if (r4 == 0) {
            u16* X = xws + (size_t)(t0 + tok) * 1024 + ch0 + cp * 2;
#pragma unroll
            for (int m = 0; m < 4; ++m)
                *(u32*)(X + m * 256) = (u32)f2bf(a[m]) | ((u32)f2bf(a[4 + m]) << 16);
        }
    }
}

// ---- LN in place on xws rows (bf16 -> bf16) -------------------------------
__global__ __launch_bounds__(256) void ln_kernel(
    u16* __restrict__ xws, const float* __restrict__ norm_g,
    const float* __restrict__ norm_b) {
    int t = blockIdx.x;
    int tid = threadIdx.x;
    int wave = tid >> 6, lane = tid & 63;
    __shared__ float red[10];
    u16* X = xws + (size_t)t * 1024;
    union { u64 w; u16 h[4]; } d;
    d.w = *(const u64*)(X + tid * 4);
    float v0 = bf2f(d.h[0]), v1 = bf2f(d.h[1]), v2 = bf2f(d.h[2]), v3 = bf2f(d.h[3]);
    float s1 = v0 + v1 + v2 + v3;
    float s2 = v0 * v0 + v1 * v1 + v2 * v2 + v3 * v3;
#pragma unroll
    for (int off = 32; off > 0; off >>= 1) {
        s1 += __shfl_down(s1, off, 64);
        s2 += __shfl_down(s2, off, 64);
    }
    if (lane == 0) { red[wave] = s1; red[4 + wave] = s2; }
    __syncthreads();
    if (tid == 0) {
        float S = red[0] + red[1] + red[2] + red[3];
        float Q = red[4] + red[5] + red[6] + red[7];
        float mean = S * (1.0f / 1024.0f);
        float var = fmaxf(Q * (1.0f / 1024.0f) - mean * mean, 0.0f);
        red[8] = mean; red[9] = rsqrtf(var + 1e-5f);
    }
    __syncthreads();
    float mean = red[8], rstd = red[9];
    float4 g = *(const float4*)&norm_g[tid * 4];
    float4 bb = *(const float4*)&norm_b[tid * 4];
    union { u64 w; u16 h[4]; } o;
    o.h[0] = f2bf((v0 - mean) * rstd * g.x + bb.x);
    o.h[1] = f2bf((v1 - mean) * rstd * g.y + bb.y);
    o.h[2] = f2bf((v2 - mean) * rstd * g.z + bb.z);
    o.h[3] = f2bf((v3 - mean) * rstd * g.w + bb.w);
    *(u64*)(X + tid * 4) = o.w;
}

// ---- 128x128 LDS-tiled GEMM X @ linT^T + bias (n-dim fastest for A reuse) -
#define GROW 40
__global__ __launch_bounds__(256) void gemm_tile_kernel(
    const u16* __restrict__ xws, const u16* __restrict__ linT,
    const float* __restrict__ lin_b, float* __restrict__ out) {
    __shared__ __align__(16) u16 As[128 * GROW];
    __shared__ __align__(16) u16 Bs[128 * GROW];
    int tid = threadIdx.x;
    int wave = tid >> 6, lane = tid & 63;
    int l15 = lane & 15, quad = lane >> 4;
    int wm = wave >> 1, wn = wave & 1;
    int m0 = blockIdx.y * 128, n0 = blockIdx.x * 128;   // x = n (4): A-tile reuse
    int sr = tid >> 2, sk = (tid & 3) * 8;

    const u16* Ap0 = xws + (size_t)(m0 + sr) * 1024 + sk;
    const u16* Ap1 = Ap0 + (size_t)64 * 1024;
    const u16* Bp0 = linT + (size_t)(n0 + sr) * 1024 + sk;
    const u16* Bp1 = Bp0 + (size_t)64 * 1024;

    floatx4 acc[4][4] = {};
    for (int kk = 0; kk < 1024; kk += 32) {
        uint4 a0 = *(const uint4*)(Ap0 + kk);
        uint4 a1 = *(const uint4*)(Ap1 + kk);
        uint4 b0 = *(const uint4*)(Bp0 + kk);
        uint4 b1 = *(const uint4*)(Bp1 + kk);
        __syncthreads();
        *(uint4*)&As[sr * GROW + sk] = a0;
        *(uint4*)&As[(64 + sr) * GROW + sk] = a1;
        *(uint4*)&Bs[sr * GROW + sk] = b0;
        *(uint4*)&Bs[(64 + sr) * GROW + sk] = b1;
        __syncthreads();
        bf16x8 af[4], bfv[4];
#pragma unroll
        for (int mi = 0; mi < 4; ++mi)
            af[mi] = *(const bf16x8*)&As[(wm * 64 + mi * 16 + l15) * GROW + quad * 8];
#pragma unroll
        for (int ni = 0; ni < 4; ++ni)
            bfv[ni] = *(const bf16x8*)&Bs[(wn * 64 + ni * 16 + l15) * GROW + quad * 8];
#pragma unroll
        for (int mi = 0; mi < 4; ++mi)
#pragma unroll
            for (int ni = 0; ni < 4; ++ni)
                acc[mi][ni] = __builtin_amdgcn_mfma_f32_16x16x32_bf16(
                    af[mi], bfv[ni], acc[mi][ni], 0, 0, 0);
    }
#pragma unroll
    for (int ni = 0; ni < 4; ++ni) {
        int col = n0 + wn * 64 + ni * 16 + l15;
        float bias = lin_b[col];
#pragma unroll
        for (int mi = 0; mi < 4; ++mi)
#pragma unroll
            for (int reg = 0; reg < 4; ++reg) {
                int row = m0 + wm * 64 + mi * 16 + quad * 4 + reg;
                out[(size_t)row * OUTD + col] = acc[mi][ni][reg] + bias;
            }
    }
}

// ---- fallback kernels (zero-workspace, round-3 proven) --------------------
__global__ __launch_bounds__(256) void key_kernel(
    const float* __restrict__ lprob, u64* __restrict__ keys) {
    int g = blockIdx.x * 256 + threadIdx.x;
    int n = g % NTOK;
    keys[g] = f_to_key(make_f(lprob[g], n), n);
}

__global__ __launch_bounds__(256) void partial_rank_kernel(
    const u64* __restrict__ keys, u32* __restrict__ part) {
    int b = blockIdx.y, z = blockIdx.z;
    int n = blockIdx.x * 256 + threadIdx.x;
    u64 my = keys[b * NTOK + n];
    const u64* kb = keys + b * NTOK + z * QTR;
    u32 cnt = 0;
    for (int t = 0; t < QTR; t += 8) {
#pragma unroll
        for (int j = 0; j < 8; ++j) cnt += (kb[t + j] > my) ? 1u : 0u;
    }
    part[(z * NB + b) * NTOK + n] = cnt;
}

__global__ __launch_bounds__(256) void finalize_kernel(
    const u32* __restrict__ part, float* __restrict__ pos_out) {
    int b = blockIdx.y;
    int n = blockIdx.x * 256 + threadIdx.x;
    int g = b * NTOK + n;
    u32 rank = part[g] + part[(NB + b) * NTOK + n] +
               part[(2 * NB + b) * NTOK + n] + part[(3 * NB + b) * NTOK + n];
    int i = n / GW, j = n % GW;
    if (rank < SAMPLEN) {
        int slot = b * KEEPN + (int)rank;
        pos_out[slot * 2 + 0] = (float)i;
        pos_out[slot * 2 + 1] = (float)j;
    }
    if (((i | j) & 3) == 0) {
        int r = (i >> 2) * 28 + (j >> 2);
        int slot = b * KEEPN + SAMPLEN + r;
        pos_out[slot * 2 + 0] = (float)i;
        pos_out[slot * 2 + 1] = (float)j;
    }
}

__global__ __launch_bounds__(256) void token_fb_kernel(
    const float* __restrict__ pos_in, u16* __restrict__ xdst,
    const int* __restrict__ member_idx, const int* __restrict__ pe_idx,
    const float* __restrict__ cmask, const float* __restrict__ lprob,
    const float* __restrict__ featf, const float* __restrict__ pre_table,
    const float* __restrict__ w1, const float* __restrict__ b1,
    const float* __restrict__ g1, const float* __restrict__ bb1,
    const float* __restrict__ norm_g, const float* __restrict__ norm_b) {
    int t = blockIdx.x;
    int b = t / KEEPN;
    int tid = threadIdx.x;
    __shared__ int mem_s[NBHD];
    __shared__ float4 w_s[NBHD];
    __shared__ float red[10];

    int n_src = (int)pos_in[t * 2 + 0] * GW + (int)pos_in[t * 2 + 1];

    if (tid < NBHD) {
        int e = (b * NTOK + n_src) * NBHD + tid;
        int mem = member_idx[e];
        int pe = pe_idx[e];
        float cm = cmask[e];
        float lpe = lprob[b * NTOK + mem];
        float z[4];
#pragma unroll
        for (int m = 0; m < 4; ++m) {
            float acc = b1[m];
#pragma unroll
            for (int d = 0; d < 5; ++d) acc += pre_table[pe * 5 + d] * w1[d * 4 + m];
            z[m] = acc;
        }
        float mean = (z[0] + z[1] + z[2] + z[3]) * 0.25f;
        float var = 0.0f;
#pragma unroll
        for (int m = 0; m < 4; ++m) { float d = z[m] - mean; var += d * d; }
        float rstd = rsqrtf(var * 0.25f + 1e-5f);
        float sc = lpe * cm;
        float wv[4];
#pragma unroll
        for (int m = 0; m < 4; ++m) {
            float y = (z[m] - mean) * rstd * g1[m] + bb1[m];
            wv[m] = 0.5f * y * (1.0f + erff(y * 0.70710678118654752f)) * sc;
        }
        w_s[tid] = make_float4(wv[0], wv[1], wv[2], wv[3]);
        mem_s[tid] = mem;
    }
    __syncthreads();

    float a0 = 0.f, a1 = 0.f, a2 = 0.f, a3 = 0.f;
    size_t base = (size_t)b * NTOK * DIM + tid;
#pragma unroll 8
    for (int k = 0; k < NBHD; ++k) {
        float g = featf[base + (size_t)mem_s[k] * DIM];
        float4 w = w_s[k];
        a0 += w.x * g; a1 += w.y * g; a2 += w.z * g; a3 += w.w * g;
    }
    float s1 = a0 + a1 + a2 + a3;
    float s2 = a0 * a0 + a1 * a1 + a2 * a2 + a3 * a3;
#pragma unroll
    for (int off = 32; off > 0; off >>= 1) {
        s1 += __shfl_down(s1, off, 64);
        s2 += __shfl_down(s2, off, 64);
    }
    int wave = tid >> 6, lane = tid & 63;
    if (lane == 0) { red[wave] = s1; red[4 + wave] = s2; }
    __syncthreads();
    if (tid == 0) {
        float S = red[0] + red[1] + red[2] + red[3];
        float Q = red[4] + red[5] + red[6] + red[7];
        float mean = S * (1.0f / 1024.0f);
        float var = fmaxf(Q * (1.0f / 1024.0f) - mean * mean, 0.0f);
        red[8] = mean; red[9] = rsqrtf(var + 1e-5f);
    }
    __syncthreads();
    float mean = red[8], rstd = red[9];
    float acc4[4] = {a0, a1, a2, a3};
    u16* Xp = xdst + (size_t)t * 1024;
#pragma unroll
    for (int m = 0; m < 4; ++m) {
        int cc = m * 256 + tid;
        float v = (acc4[m] - mean) * rstd * norm_g[cc] + norm_b[cc];
        Xp[cc] = f2bf(v);
    }
}

__global__ __launch_bounds__(256) void gemm_inplace_kernel(
    const float* __restrict__ lin_w, const float* __restrict__ lin_b,
    float* __restrict__ out) {
    __shared__ __align__(16) u16 Bs[BLKN * BROW];
    int tile_m = blockIdx.x;
    int nblk = blockIdx.y;
    int tid = threadIdx.x;
    int wave = tid >> 6, lane = tid & 63;
    int l15 = lane & 15, quad = lane >> 4;

    const u16* Xbase = (const u16*)out;
    floatx4 acc[8][4] = {};

    for (int kk = 0; kk < 1024; kk += 32) {
        __syncthreads();
#pragma unroll
        for (int it = 0; it < 4; ++it) {
            int task = it * 256 + tid;
            int kp = task >> 6;
            int ng = task & 63;
            int k = kp * 2;
            int n0 = nblk * BLKN + ng * 4;
            float4 fa = *(const float4*)&lin_w[(size_t)(kk + k) * OUTD + n0];
            float4 fb = *(const float4*)&lin_w[(size_t)(kk + k + 1) * OUTD + n0];
            u16* bp = &Bs[(ng * 4) * BROW + k];
            *(u32*)(bp + 0 * BROW) = (u32)f2bf(fa.x) | ((u32)f2bf(fb.x) << 16);
            *(u32*)(bp + 1 * BROW) = (u32)f2bf(fa.y) | ((u32)f2bf(fb.y) << 16);
            *(u32*)(bp + 2 * BROW) = (u32)f2bf(fa.z) | ((u32)f2bf(fb.z) << 16);
            *(u32*)(bp + 3 * BROW) = (u32)f2bf(fa.w) | ((u32)f2bf(fb.w) << 16);
        }
        __syncthreads();
        bf16x8 bfrag[4];
#pragma unroll
        for (int ni = 0; ni < 4; ++ni)
            bfrag[ni] = *(const bf16x8*)&Bs[(wave * 64 + ni * 16 + l15) * BROW + quad * 8];
#pragma unroll
        for (int mi = 0; mi < 8; ++mi) {
            int row = tile_m * BLKM + mi * 16 + l15;
            bf16x8 af = *(const bf16x8*)&Xbase[(size_t)row * 1024 + kk + quad * 8];
#pragma unroll
            for (int ni = 0; ni < 4; ++ni)
                acc[mi][ni] = __builtin_amdgcn_mfma_f32_16x16x32_bf16(
                    af, bfrag[ni], acc[mi][ni], 0, 0, 0);
        }
    }
    __syncthreads();
#pragma unroll
    for (int mi = 0; mi < 8; ++mi)
#pragma unroll
        for (int ni = 0; ni < 4; ++ni) {
            int col = nblk * BLKN + wave * 64 + ni * 16 + l15;
            float bias = lin_b[col];
#pragma unroll
            for (int reg = 0; reg < 4; ++reg) {
                int row = tile_m * BLKM + mi * 16 + quad * 4 + reg;
                out[(size_t)row * OUTD + col] = acc[mi][ni][reg] + bias;
            }
        }
}

extern "C" void kernel_launch(void* const* d_in, const int* in_sizes, int n_in,
                              void* d_out, int out_size, void* d_ws, size_t ws_size,
                              hipStream_t stream) {
    const float* feat     = (const float*)d_in[1];
    const int* member_idx = (const int*)d_in[2];
    const float* cmask    = (const float*)d_in[3];
    const float* lprob    = (const float*)d_in[4];
    const int* pe_idx     = (const int*)d_in[6];
    const float* pre_table= (const float*)d_in[8];
    const float* w1       = (const float*)d_in[9];
    const float* b1       = (const float*)d_in[10];
    const float* g1       = (const float*)d_in[11];
    const float* bb1      = (const float*)d_in[12];
    const float* norm_g   = (const float*)d_in[13];
    const float* norm_b   = (const float*)d_in[14];
    const float* lin_w    = (const float*)d_in[15];
    const float* lin_b    = (const float*)d_in[16];

    float* pos_out = (float*)d_out;
    float* out     = pos_out + POSN;

    if (ws_size >= WS_NEED) {
        char* ws = (char*)d_ws;
        u16*    xws   = (u16*)(ws + XWS_OFF);
        float4* wtab  = (float4*)(ws + WTAB_OFF);
        u16*    linT  = (u16*)(ws + LINT_OFF);
        u64*    slots = (u64*)(ws + SLOTS_OFF);
        u32*    hist  = (u32*)(ws + HIST_OFF);
        u32*    base  = hist + NB * NBKT;
        u32*    curs  = base + NB * NBKT;

        linT_cvt_kernel<<<dim3(16, 8), 256, 0, stream>>>(lin_w, linT, hist);
        hist_kernel<<<(NB * NTOK) / 256, 256, 0, stream>>>(lprob, hist);
        prefix_kernel<<<NB, 1024, 0, stream>>>(hist, base, curs);
        scatter_kernel<<<(NB * NTOK) / 256, 256, 0, stream>>>(lprob, curs, slots);
        rank_finalize_kernel<<<(NB * NTOK) / 256, 256, 0, stream>>>(
            lprob, hist, base, slots, pos_out);
        wtab_kernel<<<(NB * KEEPN * NBHD) / 256, 256, 0, stream>>>(
            pos_out, member_idx, pe_idx, cmask, lprob, pre_table,
            w1, b1, g1, bb1, wtab);
        token_v4_kernel<<<dim3(784, 8), 256, 0, stream>>>(
            pos_out, wtab, member_idx, feat, xws);
        ln_kernel<<<NB * KEEPN, 256, 0, stream>>>(xws, norm_g, norm_b);
        gemm_tile_kernel<<<dim3(4, 98), 256, 0, stream>>>(xws, linT, lin_b, out);
    } else {
        u64* keys = (u64*)out;
        u32* part = (u32*)((char*)out + 401408);

        key_kernel<<<(NB * NTOK) / 256, 256, 0, stream>>>(lprob, keys);
        partial_rank_kernel<<<dim3(49, NB, 4), 256, 0, stream>>>(keys, part);
        finalize_kernel<<<dim3(49, NB), 256, 0, stream>>>(part, pos_out);
        token_fb_kernel<<<NB * KEEPN, 256, 0, stream>>>(
            pos_out, (u16*)out, member_idx, pe_idx, cmask, lprob, feat,
            pre_table, w1, b1, g1, bb1, norm_g, norm_b);
        gemm_inplace_kernel<<<dim3(98, 2), 256, 0, stream>>>(lin_w, lin_b, out);
    }
}